// Round 5
// baseline (443.369 us; speedup 1.0000x reference)
//
#include <hip/hip_runtime.h>

#define NN 100000
#define EE 1600000
#define FIN 128
#define HH 64
#define NBKT 782          // ceil(NN/128) coarse buckets
#define SCHUNK 4096       // edges per block in hist/scatter passes
#define NCH 391           // ceil(EE/SCHUNK)
#define ZNODE NN          // spare all-zero table row for CSR padding
#define CSRCAP (EE + 384 * NBKT)   // padded CSR capacity

typedef unsigned int uint;
typedef unsigned short ushort;
typedef __attribute__((ext_vector_type(8))) short short8;
typedef __attribute__((ext_vector_type(4))) float float4a;
typedef __attribute__((ext_vector_type(4))) uint uint4a;

union FragU { uint4 u; short8 s; };

static __device__ __forceinline__ ushort f2bf(float f) {
    uint u = __float_as_uint(f);
    uint r = (u + 0x7fffu + ((u >> 16) & 1u)) >> 16;   // RNE
    return (ushort)r;
}
static __device__ __forceinline__ uint pack2bf(float a, float b) {
    return (uint)f2bf(a) | ((uint)f2bf(b) << 16);
}
static __device__ __forceinline__ float bf2f_lo(uint u) {
    return __uint_as_float(u << 16);
}
static __device__ __forceinline__ float bf2f_hi(uint u) {
    return __uint_as_float(u & 0xffff0000u);
}
static __device__ __forceinline__ void qadd(float* a, uint4 q) {
    a[0] += bf2f_lo(q.x); a[1] += bf2f_hi(q.x);
    a[2] += bf2f_lo(q.y); a[3] += bf2f_hi(q.y);
    a[4] += bf2f_lo(q.z); a[5] += bf2f_hi(q.z);
    a[6] += bf2f_lo(q.w); a[7] += bf2f_hi(q.w);
}
static __device__ __forceinline__ void qset(float* a, uint4 q) {
    a[0] = bf2f_lo(q.x); a[1] = bf2f_hi(q.x);
    a[2] = bf2f_lo(q.y); a[3] = bf2f_hi(q.y);
    a[4] = bf2f_lo(q.z); a[5] = bf2f_hi(q.z);
    a[6] = bf2f_lo(q.w); a[7] = bf2f_hi(q.w);
}

// ---------------- zero two int arrays ----------------
__global__ __launch_bounds__(256) void zero2_kernel(int* __restrict__ a, int* __restrict__ b, int n) {
    int i = blockIdx.x * blockDim.x + threadIdx.x;
    if (i < n) { a[i] = 0; b[i] = 0; }
}

// ---------------- pass 1: coarse bucket histogram, both sets, int4 reads ----------------
__global__ __launch_bounds__(256) void bhist_kernel(const int* __restrict__ pri, const int* __restrict__ sup,
                                                    int* __restrict__ ghp, int* __restrict__ ghs) {
    __shared__ int h[NBKT];
    int bid = blockIdx.x;
    int set = (bid >= NCH) ? 1 : 0;
    int chunk = bid - set * NCH;
    const int* col = (set ? sup : pri) + EE;
    int* gh = set ? ghs : ghp;
    int t = threadIdx.x;
    for (int i = t; i < NBKT; i += 256) h[i] = 0;
    __syncthreads();
    int e0 = chunk * SCHUNK;
    int e1 = min(e0 + SCHUNK, EE);
    for (int e = e0 + t * 4; e < e1; e += 1024) {
        int4 c4 = *(const int4*)(col + e);
        atomicAdd(&h[c4.x >> 7], 1);
        atomicAdd(&h[c4.y >> 7], 1);
        atomicAdd(&h[c4.z >> 7], 1);
        atomicAdd(&h[c4.w >> 7], 1);
    }
    __syncthreads();
    for (int i = t; i < NBKT; i += 256) {
        int v = h[i];
        if (v) atomicAdd(&gh[i], v);
    }
}

// ---------------- pass 2: bucket base scan, block 0 = pri, block 1 = sup ----------------
__global__ __launch_bounds__(1024) void bscan_kernel(const int* __restrict__ ghp, int* __restrict__ gbp, int* __restrict__ gcp,
                                                     const int* __restrict__ ghs, int* __restrict__ gbs, int* __restrict__ gcs) {
    __shared__ int s[1024];
    const int* gh = blockIdx.x ? ghs : ghp;
    int* gb = blockIdx.x ? gbs : gbp;
    int* gc = blockIdx.x ? gcs : gcp;
    int t = threadIdx.x;
    int v = (t < NBKT) ? gh[t] : 0;
    s[t] = v;
    __syncthreads();
    for (int d = 1; d < 1024; d <<= 1) {
        int a = (t >= d) ? s[t - d] : 0;
        __syncthreads();
        s[t] += a;
        __syncthreads();
    }
    int excl = s[t] - v;
    if (t <= NBKT) gb[t] = excl;   // gb[NBKT] = EE
    if (t < NBKT) gc[t] = excl;
}

// ---------------- pass 3: binned scatter (packed uint: row | fine<<17), both sets ----------------
__global__ __launch_bounds__(256) void bscatter_kernel(const int* __restrict__ pri, const int* __restrict__ sup,
                                                       int* __restrict__ gcp, int* __restrict__ gcs,
                                                       uint* __restrict__ pkp, uint* __restrict__ pks) {
    __shared__ int h[NBKT];
    __shared__ int basec[NBKT];
    int bid = blockIdx.x;
    int set = (bid >= NCH) ? 1 : 0;
    int chunk = bid - set * NCH;
    const int* row = set ? sup : pri;
    const int* col = row + EE;
    int* gcur = set ? gcs : gcp;
    uint* packed = set ? pks : pkp;
    int t = threadIdx.x;
    for (int i = t; i < NBKT; i += 256) h[i] = 0;
    __syncthreads();
    int e0 = chunk * SCHUNK;
    int e1 = min(e0 + SCHUNK, EE);
    for (int e = e0 + t * 4; e < e1; e += 1024) {
        int4 c4 = *(const int4*)(col + e);
        atomicAdd(&h[c4.x >> 7], 1);
        atomicAdd(&h[c4.y >> 7], 1);
        atomicAdd(&h[c4.z >> 7], 1);
        atomicAdd(&h[c4.w >> 7], 1);
    }
    __syncthreads();
    for (int i = t; i < NBKT; i += 256) {
        int v = h[i];
        basec[i] = v ? atomicAdd(&gcur[i], v) : 0;
    }
    __syncthreads();
    for (int i = t; i < NBKT; i += 256) h[i] = 0;
    __syncthreads();
    for (int e = e0 + t * 4; e < e1; e += 1024) {
        int4 c4 = *(const int4*)(col + e);
        int4 r4 = *(const int4*)(row + e);
        int b0 = c4.x >> 7, b1 = c4.y >> 7, b2 = c4.z >> 7, b3 = c4.w >> 7;
        int p0 = basec[b0] + atomicAdd(&h[b0], 1);
        int p1 = basec[b1] + atomicAdd(&h[b1], 1);
        int p2 = basec[b2] + atomicAdd(&h[b2], 1);
        int p3 = basec[b3] + atomicAdd(&h[b3], 1);
        packed[p0] = (uint)r4.x | ((uint)(c4.x & 127) << 17);
        packed[p1] = (uint)r4.y | ((uint)(c4.y & 127) << 17);
        packed[p2] = (uint)r4.z | ((uint)(c4.z & 127) << 17);
        packed[p3] = (uint)r4.w | ((uint)(c4.w & 127) << 17);
    }
}

// ---------------- pass 4: per-bucket CSR finalize (padded to x4 with ZNODE) ----------------
__global__ __launch_bounds__(256) void bfinal_kernel(const uint* __restrict__ pkp, const int* __restrict__ gbp,
                                                     int* __restrict__ cntp, int* __restrict__ offp, int* __restrict__ csrp,
                                                     const uint* __restrict__ pks, const int* __restrict__ gbs,
                                                     int* __restrict__ cnts, int* __restrict__ offs, int* __restrict__ csrs) {
    __shared__ int h[128];
    __shared__ int sc[128];
    int bid = blockIdx.x;
    int set = (bid >= NBKT) ? 1 : 0;
    int b = bid - set * NBKT;
    const uint* packed = set ? pks : pkp;
    const int* gbase = set ? gbs : gbp;
    int* cnt = set ? cnts : cntp;
    int* off = set ? offs : offp;
    int* csr = set ? csrs : csrp;
    int t = threadIdx.x;
    int s0 = gbase[b], s1 = gbase[b + 1];
    int pb = s0 + 384 * b;          // padded segment base (max pad 3*128 per bucket)
    if (t < 128) h[t] = 0;
    __syncthreads();
    for (int e = s0 + t; e < s1; e += 256) atomicAdd(&h[(packed[e] >> 17) & 127], 1);
    __syncthreads();
    int hv = 0, hp = 0;
    if (t < 128) { hv = h[t]; hp = (hv + 3) & ~3; sc[t] = hp; }
    __syncthreads();
    for (int d = 1; d < 128; d <<= 1) {
        int a = (t >= d && t < 128) ? sc[t - d] : 0;
        __syncthreads();
        if (t < 128) sc[t] += a;
        __syncthreads();
    }
    int excl = 0;
    if (t < 128) excl = sc[t] - hp;
    __syncthreads();
    if (t < 128) h[t] = excl;      // per-node cursor (padded layout)
    int node = b * 128 + t;
    if (t < 128 && node < NN) {
        cnt[node] = hv;            // TRUE degree (dinv / self coeffs)
        off[node] = pb + excl;
    }
    __syncthreads();
    for (int e = s0 + t; e < s1; e += 256) {
        uint pc = packed[e];
        int rk = atomicAdd(&h[(pc >> 17) & 127], 1);
        csr[pb + rk] = (int)(pc & 0x1FFFFu);
    }
    // pad fill [cnt, cntpad) with ZNODE (disjoint slots, no sync needed)
    if (t < 128 && node < NN) {
        for (int j = hv; j < hp; j++) csr[pb + excl + j] = ZNODE;
    }
}

// ---------------- dinv (3 configs) + zero spare table rows ----------------
__global__ __launch_bounds__(256) void dinv_kernel(const int* __restrict__ cp, const int* __restrict__ cs,
                                                   float* __restrict__ dp1, float* __restrict__ dp2,
                                                   float* __restrict__ ds2,
                                                   ushort* __restrict__ gA, ushort* __restrict__ g2s,
                                                   ushort* __restrict__ gB, ushort* __restrict__ gts, int n) {
    int i = blockIdx.x * blockDim.x + threadIdx.x;
    if (i < n) {
        float fp = (float)cp[i];
        float fs = (float)cs[i];
        dp1[i] = rsqrtf(fp + 0.3f);
        dp2[i] = rsqrtf(fp + 0.5f);
        ds2[i] = rsqrtf(fs + 0.5f);
    }
    if (blockIdx.x == 0) {
        int t = threadIdx.x;
        uint* za = (uint*)(gA  + (size_t)ZNODE * 128);
        uint* zb = (uint*)(gB  + (size_t)ZNODE * 128);
        uint* zs = (uint*)(g2s + (size_t)ZNODE * 64);
        uint* zt = (uint*)(gts + (size_t)ZNODE * 64);
        if (t < 64)       za[t] = 0;
        else if (t < 128) zb[t - 64] = 0;
        else if (t < 160) zs[t - 128] = 0;
        else if (t < 192) zt[t - 160] = 0;
    }
}

// ---------------- W -> bf16 B-fragment-major conversion ----------------
__global__ __launch_bounds__(256) void wconv_kernel(const float* __restrict__ w1,
                                                    const float* __restrict__ w2,
                                                    uint4* __restrict__ wfrag) {
    int u = blockIdx.x * 256 + threadIdx.x;   // 0..2047
    if (u >= 2048) return;
    int lane = u & 63;
    int ks   = (u >> 6) & 3;
    int ct   = u >> 8;
    int c    = ct * 16 + (lane & 15);
    int k0   = ks * 32 + (lane >> 4) * 8;
    const float* src = (c < 64) ? (w1 + c * 128 + k0) : (w2 + (c - 64) * 128 + k0);
    float4 p0 = ((const float4*)src)[0];
    float4 p1 = ((const float4*)src)[1];
    uint4 q;
    q.x = pack2bf(p0.x, p0.y);
    q.y = pack2bf(p0.z, p0.w);
    q.z = pack2bf(p1.x, p1.y);
    q.w = pack2bf(p1.z, p1.w);
    wfrag[u] = q;
}

// ---------------- MFMA dual GEMM -> bf16 g-tables (gA interleaved 256B rows + g2s) ----------------
// gA row layout per node (128 ushorts): [0..63] = g1 = h1*dp1, [64..127] = g2p = h2*dp2
__global__ __launch_bounds__(256) void gemm_kernel(const float* __restrict__ x,
                                                   const uint4* __restrict__ wfrag,
                                                   const float* __restrict__ b1, const float* __restrict__ b2,
                                                   const float* __restrict__ dp1, const float* __restrict__ dp2,
                                                   const float* __restrict__ ds2,
                                                   ushort* __restrict__ gA, ushort* __restrict__ g2s) {
    __shared__ uint4 alds[32 * 68];   // 34 KB, 17-unit swizzle
    int t = threadIdx.x;
    int lane = t & 63;
    int wave = t >> 6;
    int row0 = blockIdx.x * 128;

    FragU bfrag[2][4];
#pragma unroll
    for (int ctl = 0; ctl < 2; ctl++)
#pragma unroll
        for (int ks = 0; ks < 4; ks++)
            bfrag[ctl][ks].u = wfrag[((wave * 2 + ctl) * 4 + ks) * 64 + lane];

    {
        int m = t >> 4;
        int g = t & 15;
        const float4* xv = (const float4*)x;
#pragma unroll
        for (int s = 0; s < 8; s++) {
            int r = row0 + s * 16 + m;
            int rc = (r < NN) ? r : (NN - 1);
            float4 p0 = xv[rc * 32 + g * 2];
            float4 p1 = xv[rc * 32 + g * 2 + 1];
            uint4 q;
            q.x = pack2bf(p0.x, p0.y);
            q.y = pack2bf(p0.z, p0.w);
            q.z = pack2bf(p1.x, p1.y);
            q.w = pack2bf(p1.z, p1.w);
            alds[(s * 4 + (g >> 2)) * 68 + (g & 3) * 17 + m] = q;
        }
    }
    __syncthreads();

    int cA = (wave * 2 + 0) * 16 + (lane & 15);
    int cB = cA + 16;
    float biasA = (wave < 2) ? b1[cA] : b2[cA - 64];
    float biasB = (wave < 2) ? b1[cB] : b2[cB - 64];
    float4a acc[8][2];
#pragma unroll
    for (int rt = 0; rt < 8; rt++) {
        acc[rt][0] = float4a{biasA, biasA, biasA, biasA};
        acc[rt][1] = float4a{biasB, biasB, biasB, biasB};
    }

    int quad = lane >> 4;
    int asig = quad * 17 + (lane & 15);
#pragma unroll
    for (int rt = 0; rt < 8; rt++) {
        FragU af[4];
#pragma unroll
        for (int ks = 0; ks < 4; ks++)
            af[ks].u = alds[(rt * 4 + ks) * 68 + asig];
#pragma unroll
        for (int ks = 0; ks < 4; ks++) {
            acc[rt][0] = __builtin_amdgcn_mfma_f32_16x16x32_bf16(af[ks].s, bfrag[0][ks].s, acc[rt][0], 0, 0, 0);
            acc[rt][1] = __builtin_amdgcn_mfma_f32_16x16x32_bf16(af[ks].s, bfrag[1][ks].s, acc[rt][1], 0, 0, 0);
        }
    }

#pragma unroll
    for (int rt = 0; rt < 8; rt++) {
        int rb = row0 + rt * 16 + quad * 4;
#pragma unroll
        for (int ctl = 0; ctl < 2; ctl++) {
            int c = (wave * 2 + ctl) * 16 + (lane & 15);
#pragma unroll
            for (int reg = 0; reg < 4; reg++) {
                int r = rb + reg;
                if (r >= NN) continue;
                float v = acc[rt][ctl][reg];
                if (wave < 2) {
                    gA[r * 128 + c] = f2bf(v * dp1[r]);              // g1 half
                } else {
                    int cc = c - 64;
                    gA[r * 128 + 64 + cc] = f2bf(v * dp2[r]);        // g2p half
                    g2s[r * 64 + cc] = f2bf(v * ds2[r]);
                }
            }
        }
    }
}

// ---------------- fused hop 1: pri pair from gA (256B rows), sup from g2s ----------------
// padded CSR -> tail-free loops; writes gB + gts
__global__ __launch_bounds__(256) void spmm1_kernel(
        const uint* __restrict__ gA, const uint* __restrict__ g2s,
        ushort* __restrict__ gB, ushort* __restrict__ gts,
        const int* __restrict__ off_p, const int* __restrict__ cnt_p, const int* __restrict__ csr_p,
        const int* __restrict__ off_s, const int* __restrict__ cnt_s, const int* __restrict__ csr_s,
        const float* __restrict__ dvp1, const float* __restrict__ dvp2, const float* __restrict__ dvs2) {
    int tid = blockIdx.x * 256 + threadIdx.x;
    int node = tid >> 3;
    if (node >= NN) return;
    int fc = tid & 7;
    const uint4* gav = (const uint4*)gA;
    const uint4* gsv = (const uint4*)g2s;

    // self rows: issue early (independent of loops)
    uint4 qself1 = gav[node * 16 + fc];
    uint4 qself2 = gav[node * 16 + 8 + fc];

    float a1[8] = {0, 0, 0, 0, 0, 0, 0, 0};
    float ap[8] = {0, 0, 0, 0, 0, 0, 0, 0};
    float as[8] = {0, 0, 0, 0, 0, 0, 0, 0};

    {   // pri edges: one 256B combined row per edge; padded, no tail
        int o = off_p[node];
        int cp4 = (cnt_p[node] + 3) & ~3;
        for (int e = 0; e < cp4; e += 2) {
            int s0 = csr_p[o + e], s1 = csr_p[o + e + 1];
            uint4 qa0 = gav[s0 * 16 + fc];
            uint4 qb0 = gav[s0 * 16 + 8 + fc];
            uint4 qa1 = gav[s1 * 16 + fc];
            uint4 qb1 = gav[s1 * 16 + 8 + fc];
            qadd(a1, qa0); qadd(ap, qb0);
            qadd(a1, qa1); qadd(ap, qb1);
        }
    }
    {   // sup edges: padded, no tail
        int o = off_s[node];
        int cp4 = (cnt_s[node] + 3) & ~3;
        for (int e = 0; e < cp4; e += 4) {
            int s0 = csr_s[o + e],     s1 = csr_s[o + e + 1];
            int s2 = csr_s[o + e + 2], s3 = csr_s[o + e + 3];
            uint4 q0 = gsv[s0 * 8 + fc];
            uint4 q1 = gsv[s1 * 8 + fc];
            uint4 q2 = gsv[s2 * 8 + fc];
            uint4 q3 = gsv[s3 * 8 + fc];
            qadd(as, q0); qadd(as, q1); qadd(as, q2); qadd(as, q3);
        }
    }

    float dp1 = dvp1[node], dp2 = dvp2[node], ds2 = dvs2[node];
    float sp1 = 0.7f + 0.3f * dp1 * dp1;
    float sp2 = 0.5f + 0.5f * dp2 * dp2;
    float ss2 = 0.5f + 0.5f * ds2 * ds2;
    // self-term coefficients applied directly to own table rows: h = g_own/d
    float c1 = sp1 / dp1;
    float cp = sp2 / dp2;
    float cs = ss2 / dp2;   // z2s self uses h2 = g2p_own/dp2

    float t1f[8], tpf[8];
    qset(t1f, qself1);
    qset(tpf, qself2);

    float o1[8], op[8], os[8];
#pragma unroll
    for (int i = 0; i < 8; i++) {
        o1[i] = c1 * t1f[i] + dp1 * a1[i];
        op[i] = cp * tpf[i] + dp2 * ap[i];
        os[i] = cs * tpf[i] + ds2 * as[i];
    }

    uint4a q;
    q.x = pack2bf(o1[0] * dp1, o1[1] * dp1);
    q.y = pack2bf(o1[2] * dp1, o1[3] * dp1);
    q.z = pack2bf(o1[4] * dp1, o1[5] * dp1);
    q.w = pack2bf(o1[6] * dp1, o1[7] * dp1);
    __builtin_nontemporal_store(q, ((uint4a*)gB) + node * 16 + fc);
    q.x = pack2bf(op[0] * dp2, op[1] * dp2);
    q.y = pack2bf(op[2] * dp2, op[3] * dp2);
    q.z = pack2bf(op[4] * dp2, op[5] * dp2);
    q.w = pack2bf(op[6] * dp2, op[7] * dp2);
    __builtin_nontemporal_store(q, ((uint4a*)gB) + node * 16 + 8 + fc);
    q.x = pack2bf(os[0] * ds2, os[1] * ds2);
    q.y = pack2bf(os[2] * ds2, os[3] * ds2);
    q.z = pack2bf(os[4] * ds2, os[5] * ds2);
    q.w = pack2bf(os[6] * ds2, os[7] * ds2);
    __builtin_nontemporal_store(q, ((uint4a*)gts) + node * 8 + fc);
}

// ---------------- fused hop 2: final outputs, pri pair from gB, sup from gts ----------------
__global__ __launch_bounds__(256) void spmm2_kernel(
        const uint* __restrict__ gB, const uint* __restrict__ gts,
        const int* __restrict__ off_p, const int* __restrict__ cnt_p, const int* __restrict__ csr_p,
        const int* __restrict__ off_s, const int* __restrict__ cnt_s, const int* __restrict__ csr_s,
        const float* __restrict__ dvp1, const float* __restrict__ dvp2, const float* __restrict__ dvs2,
        float* __restrict__ out1, float* __restrict__ out2) {
    int tid = blockIdx.x * 256 + threadIdx.x;
    int node = tid >> 3;
    if (node >= NN) return;
    int fc = tid & 7;
    const uint4* gbv = (const uint4*)gB;
    const uint4* gsv = (const uint4*)gts;

    // self rows: issue early
    uint4 qself1 = gbv[node * 16 + fc];
    uint4 qself2 = gbv[node * 16 + 8 + fc];
    uint4 qself3 = gsv[node * 8 + fc];

    float a1[8] = {0, 0, 0, 0, 0, 0, 0, 0};
    float ap[8] = {0, 0, 0, 0, 0, 0, 0, 0};
    float as[8] = {0, 0, 0, 0, 0, 0, 0, 0};

    {   // pri edges: one 256B combined row per edge; padded, no tail
        int o = off_p[node];
        int cp4 = (cnt_p[node] + 3) & ~3;
        for (int e = 0; e < cp4; e += 2) {
            int s0 = csr_p[o + e], s1 = csr_p[o + e + 1];
            uint4 qa0 = gbv[s0 * 16 + fc];
            uint4 qb0 = gbv[s0 * 16 + 8 + fc];
            uint4 qa1 = gbv[s1 * 16 + fc];
            uint4 qb1 = gbv[s1 * 16 + 8 + fc];
            qadd(a1, qa0); qadd(ap, qb0);
            qadd(a1, qa1); qadd(ap, qb1);
        }
    }
    {   // sup edges: padded, no tail
        int o = off_s[node];
        int cp4 = (cnt_s[node] + 3) & ~3;
        for (int e = 0; e < cp4; e += 4) {
            int s0 = csr_s[o + e],     s1 = csr_s[o + e + 1];
            int s2 = csr_s[o + e + 2], s3 = csr_s[o + e + 3];
            uint4 q0 = gsv[s0 * 8 + fc];
            uint4 q1 = gsv[s1 * 8 + fc];
            uint4 q2 = gsv[s2 * 8 + fc];
            uint4 q3 = gsv[s3 * 8 + fc];
            qadd(as, q0); qadd(as, q1); qadd(as, q2); qadd(as, q3);
        }
    }

    float dp1 = dvp1[node], dp2 = dvp2[node], ds2 = dvs2[node];
    float sp1 = 0.7f + 0.3f * dp1 * dp1;
    float sp2 = 0.5f + 0.5f * dp2 * dp2;
    float ss2 = 0.5f + 0.5f * ds2 * ds2;
    float c1 = sp1 / dp1;
    float cp = sp2 / dp2;
    float cs = ss2 / ds2;

    float t1f[8], tpf[8], tsf[8];
    qset(t1f, qself1);
    qset(tpf, qself2);
    qset(tsf, qself3);

    float oz1[8], oz2[8];
#pragma unroll
    for (int i = 0; i < 8; i++) {
        oz1[i] = c1 * t1f[i] + dp1 * a1[i];
        oz2[i] = (cp * tpf[i] + dp2 * ap[i]) + (cs * tsf[i] + ds2 * as[i]);
    }

    float4a* o1v = (float4a*)out1;
    float4a* o2v = (float4a*)out2;
    float4a v;
    v.x = oz1[0]; v.y = oz1[1]; v.z = oz1[2]; v.w = oz1[3];
    __builtin_nontemporal_store(v, o1v + node * 16 + fc * 2);
    v.x = oz1[4]; v.y = oz1[5]; v.z = oz1[6]; v.w = oz1[7];
    __builtin_nontemporal_store(v, o1v + node * 16 + fc * 2 + 1);
    v.x = oz2[0]; v.y = oz2[1]; v.z = oz2[2]; v.w = oz2[3];
    __builtin_nontemporal_store(v, o2v + node * 16 + fc * 2);
    v.x = oz2[4]; v.y = oz2[5]; v.z = oz2[6]; v.w = oz2[7];
    __builtin_nontemporal_store(v, o2v + node * 16 + fc * 2 + 1);
}

extern "C" void kernel_launch(void* const* d_in, const int* in_sizes, int n_in,
                              void* d_out, int out_size, void* d_ws, size_t ws_size,
                              hipStream_t stream) {
    const float* x  = (const float*)d_in[0];
    const int* pri  = (const int*)d_in[1];
    const int* sup  = (const int*)d_in[2];
    const float* w1 = (const float*)d_in[3];
    const float* b1 = (const float*)d_in[4];
    const float* w2 = (const float*)d_in[5];
    const float* b2 = (const float*)d_in[6];
    float* out = (float*)d_out;

    char* ws = (char*)d_ws;
    auto alloc = [&](size_t bytes) -> char* {
        char* p = ws;
        ws += (bytes + 255) & ~(size_t)255;
        return p;
    };
    int* cnt_p  = (int*)alloc(NN * 4);
    int* cnt_s  = (int*)alloc(NN * 4);
    int* off_p  = (int*)alloc(NN * 4);
    int* off_s  = (int*)alloc(NN * 4);
    int* ghist_p = (int*)alloc((NBKT + 1) * 4);
    int* ghist_s = (int*)alloc((NBKT + 1) * 4);
    int* gbase_p = (int*)alloc((NBKT + 1) * 4);
    int* gbase_s = (int*)alloc((NBKT + 1) * 4);
    int* gcur_p  = (int*)alloc((NBKT + 1) * 4);
    int* gcur_s  = (int*)alloc((NBKT + 1) * 4);
    int* csr_p  = (int*)alloc((size_t)CSRCAP * 4);
    int* csr_s  = (int*)alloc((size_t)CSRCAP * 4);
    float* dv_p1 = (float*)alloc(NN * 4);
    float* dv_p2 = (float*)alloc(NN * 4);
    float* dv_s2 = (float*)alloc(NN * 4);
    uint4* wfrag = (uint4*)alloc(2048 * 16);
    ushort* gA  = (ushort*)alloc((size_t)(NN + 1) * 128 * 2);   // [g1|g2p] interleaved + zero row
    ushort* g2s = (ushort*)alloc((size_t)(NN + 1) * HH * 2);
    ushort* gB  = (ushort*)alloc((size_t)(NN + 1) * 128 * 2);   // [gt1|gtp] interleaved + zero row
    ushort* gts = (ushort*)alloc((size_t)(NN + 1) * HH * 2);
    // packed buffers alias hop-1 outputs (consumed by bfinal before spmm1 writes them;
    // zero rows live beyond the 6.4 MB packed regions)
    uint* packed_p = (uint*)gB;    // 6.4 MB <= 25.6 MB
    uint* packed_s = (uint*)gts;   // 6.4 MB <= 12.8 MB

    const int NB_N = (NN + 255) / 256;
    const int NB_SPMM = (NN * 8 + 255) / 256;       // 3125
    const int NB_GEMM = (NN + 127) / 128;           // 782

    // --- CSR build (two-level counting sort, both sets per launch) ---
    zero2_kernel<<<(NBKT + 255) / 256, 256, 0, stream>>>(ghist_p, ghist_s, NBKT);
    bhist_kernel<<<2 * NCH, 256, 0, stream>>>(pri, sup, ghist_p, ghist_s);
    bscan_kernel<<<2, 1024, 0, stream>>>(ghist_p, gbase_p, gcur_p, ghist_s, gbase_s, gcur_s);
    bscatter_kernel<<<2 * NCH, 256, 0, stream>>>(pri, sup, gcur_p, gcur_s, packed_p, packed_s);
    bfinal_kernel<<<2 * NBKT, 256, 0, stream>>>(packed_p, gbase_p, cnt_p, off_p, csr_p,
                                                packed_s, gbase_s, cnt_s, off_s, csr_s);

    dinv_kernel<<<NB_N, 256, 0, stream>>>(cnt_p, cnt_s, dv_p1, dv_p2, dv_s2,
                                          gA, g2s, gB, gts, NN);

    // --- W conversion + MFMA dual GEMM (interleaved gA + g2s) ---
    wconv_kernel<<<8, 256, 0, stream>>>(w1, w2, wfrag);
    gemm_kernel<<<NB_GEMM, 256, 0, stream>>>(x, wfrag, b1, b2, dv_p1, dv_p2, dv_s2,
                                             gA, g2s);

    // --- fused hop 1 (3 branches) + fused hop 2 (final z1, z2) ---
    spmm1_kernel<<<NB_SPMM, 256, 0, stream>>>((const uint*)gA, (const uint*)g2s,
                                              gB, gts,
                                              off_p, cnt_p, csr_p, off_s, cnt_s, csr_s,
                                              dv_p1, dv_p2, dv_s2);
    spmm2_kernel<<<NB_SPMM, 256, 0, stream>>>((const uint*)gB, (const uint*)gts,
                                              off_p, cnt_p, csr_p, off_s, cnt_s, csr_s,
                                              dv_p1, dv_p2, dv_s2,
                                              out, out + (size_t)NN * HH);
}

// Round 6
// 429.385 us; speedup vs baseline: 1.0326x; 1.0326x over previous
//
#include <hip/hip_runtime.h>

#define NN 100000
#define EE 1600000
#define FIN 128
#define HH 64
#define NBKT 782          // ceil(NN/128) coarse buckets
#define SCHUNK 4096       // edges per block in hist/scatter passes
#define NCH 391           // ceil(EE/SCHUNK)

typedef unsigned int uint;
typedef unsigned short ushort;
typedef __attribute__((ext_vector_type(8))) short short8;
typedef __attribute__((ext_vector_type(4))) float float4a;
typedef __attribute__((ext_vector_type(4))) uint uint4a;

union FragU { uint4 u; short8 s; };

static __device__ __forceinline__ ushort f2bf(float f) {
    uint u = __float_as_uint(f);
    uint r = (u + 0x7fffu + ((u >> 16) & 1u)) >> 16;   // RNE
    return (ushort)r;
}
static __device__ __forceinline__ uint pack2bf(float a, float b) {
    return (uint)f2bf(a) | ((uint)f2bf(b) << 16);
}
static __device__ __forceinline__ float bf2f_lo(uint u) {
    return __uint_as_float(u << 16);
}
static __device__ __forceinline__ float bf2f_hi(uint u) {
    return __uint_as_float(u & 0xffff0000u);
}
static __device__ __forceinline__ void qadd(float* a, uint4 q) {
    a[0] += bf2f_lo(q.x); a[1] += bf2f_hi(q.x);
    a[2] += bf2f_lo(q.y); a[3] += bf2f_hi(q.y);
    a[4] += bf2f_lo(q.z); a[5] += bf2f_hi(q.z);
    a[6] += bf2f_lo(q.w); a[7] += bf2f_hi(q.w);
}
static __device__ __forceinline__ void qset(float* a, uint4 q) {
    a[0] = bf2f_lo(q.x); a[1] = bf2f_hi(q.x);
    a[2] = bf2f_lo(q.y); a[3] = bf2f_hi(q.y);
    a[4] = bf2f_lo(q.z); a[5] = bf2f_hi(q.z);
    a[6] = bf2f_lo(q.w); a[7] = bf2f_hi(q.w);
}

// ---------------- fused: zero hist arrays (blocks 0-3) + W->bf16 fragment conversion (blocks 4-11) ----------------
__global__ __launch_bounds__(256) void zerowconv_kernel(int* __restrict__ a, int* __restrict__ b, int n,
                                                        const float* __restrict__ w1, const float* __restrict__ w2,
                                                        uint4* __restrict__ wfrag) {
    int bid = blockIdx.x;
    int t = threadIdx.x;
    if (bid < 4) {
        int i = bid * 256 + t;
        if (i < n) { a[i] = 0; b[i] = 0; }
        return;
    }
    int u = (bid - 4) * 256 + t;   // 0..2047
    if (u >= 2048) return;
    int lane = u & 63;
    int ks   = (u >> 6) & 3;
    int ct   = u >> 8;
    int c    = ct * 16 + (lane & 15);
    int k0   = ks * 32 + (lane >> 4) * 8;
    const float* src = (c < 64) ? (w1 + c * 128 + k0) : (w2 + (c - 64) * 128 + k0);
    float4 p0 = ((const float4*)src)[0];
    float4 p1 = ((const float4*)src)[1];
    uint4 q;
    q.x = pack2bf(p0.x, p0.y);
    q.y = pack2bf(p0.z, p0.w);
    q.z = pack2bf(p1.x, p1.y);
    q.w = pack2bf(p1.z, p1.w);
    wfrag[u] = q;
}

// ---------------- pass 1: coarse bucket histogram, both sets, int4 reads ----------------
__global__ __launch_bounds__(256) void bhist_kernel(const int* __restrict__ pri, const int* __restrict__ sup,
                                                    int* __restrict__ ghp, int* __restrict__ ghs) {
    __shared__ int h[NBKT];
    int bid = blockIdx.x;
    int set = (bid >= NCH) ? 1 : 0;
    int chunk = bid - set * NCH;
    const int* col = (set ? sup : pri) + EE;
    int* gh = set ? ghs : ghp;
    int t = threadIdx.x;
    for (int i = t; i < NBKT; i += 256) h[i] = 0;
    __syncthreads();
    int e0 = chunk * SCHUNK;
    int e1 = min(e0 + SCHUNK, EE);
    for (int e = e0 + t * 4; e < e1; e += 1024) {
        int4 c4 = *(const int4*)(col + e);
        atomicAdd(&h[c4.x >> 7], 1);
        atomicAdd(&h[c4.y >> 7], 1);
        atomicAdd(&h[c4.z >> 7], 1);
        atomicAdd(&h[c4.w >> 7], 1);
    }
    __syncthreads();
    for (int i = t; i < NBKT; i += 256) {
        int v = h[i];
        if (v) atomicAdd(&gh[i], v);
    }
}

// ---------------- pass 2: bucket base scan, block 0 = pri, block 1 = sup ----------------
__global__ __launch_bounds__(1024) void bscan_kernel(const int* __restrict__ ghp, int* __restrict__ gbp, int* __restrict__ gcp,
                                                     const int* __restrict__ ghs, int* __restrict__ gbs, int* __restrict__ gcs) {
    __shared__ int s[1024];
    const int* gh = blockIdx.x ? ghs : ghp;
    int* gb = blockIdx.x ? gbs : gbp;
    int* gc = blockIdx.x ? gcs : gcp;
    int t = threadIdx.x;
    int v = (t < NBKT) ? gh[t] : 0;
    s[t] = v;
    __syncthreads();
    for (int d = 1; d < 1024; d <<= 1) {
        int a = (t >= d) ? s[t - d] : 0;
        __syncthreads();
        s[t] += a;
        __syncthreads();
    }
    int excl = s[t] - v;
    if (t <= NBKT) gb[t] = excl;   // gb[NBKT] = EE
    if (t < NBKT) gc[t] = excl;
}

// ---------------- pass 3: binned scatter (packed uint: row | fine<<17), both sets ----------------
__global__ __launch_bounds__(256) void bscatter_kernel(const int* __restrict__ pri, const int* __restrict__ sup,
                                                       int* __restrict__ gcp, int* __restrict__ gcs,
                                                       uint* __restrict__ pkp, uint* __restrict__ pks) {
    __shared__ int h[NBKT];
    __shared__ int basec[NBKT];
    int bid = blockIdx.x;
    int set = (bid >= NCH) ? 1 : 0;
    int chunk = bid - set * NCH;
    const int* row = set ? sup : pri;
    const int* col = row + EE;
    int* gcur = set ? gcs : gcp;
    uint* packed = set ? pks : pkp;
    int t = threadIdx.x;
    for (int i = t; i < NBKT; i += 256) h[i] = 0;
    __syncthreads();
    int e0 = chunk * SCHUNK;
    int e1 = min(e0 + SCHUNK, EE);
    for (int e = e0 + t * 4; e < e1; e += 1024) {
        int4 c4 = *(const int4*)(col + e);
        atomicAdd(&h[c4.x >> 7], 1);
        atomicAdd(&h[c4.y >> 7], 1);
        atomicAdd(&h[c4.z >> 7], 1);
        atomicAdd(&h[c4.w >> 7], 1);
    }
    __syncthreads();
    for (int i = t; i < NBKT; i += 256) {
        int v = h[i];
        basec[i] = v ? atomicAdd(&gcur[i], v) : 0;
    }
    __syncthreads();
    for (int i = t; i < NBKT; i += 256) h[i] = 0;
    __syncthreads();
    for (int e = e0 + t * 4; e < e1; e += 1024) {
        int4 c4 = *(const int4*)(col + e);
        int4 r4 = *(const int4*)(row + e);
        int b0 = c4.x >> 7, b1 = c4.y >> 7, b2 = c4.z >> 7, b3 = c4.w >> 7;
        int p0 = basec[b0] + atomicAdd(&h[b0], 1);
        int p1 = basec[b1] + atomicAdd(&h[b1], 1);
        int p2 = basec[b2] + atomicAdd(&h[b2], 1);
        int p3 = basec[b3] + atomicAdd(&h[b3], 1);
        packed[p0] = (uint)r4.x | ((uint)(c4.x & 127) << 17);
        packed[p1] = (uint)r4.y | ((uint)(c4.y & 127) << 17);
        packed[p2] = (uint)r4.z | ((uint)(c4.z & 127) << 17);
        packed[p3] = (uint)r4.w | ((uint)(c4.w & 127) << 17);
    }
}

// ---------------- pass 4: per-bucket CSR finalize + cnt/off + fused dinv, both sets ----------------
__global__ __launch_bounds__(256) void bfinal_kernel(const uint* __restrict__ pkp, const int* __restrict__ gbp,
                                                     int* __restrict__ cntp, int* __restrict__ offp, int* __restrict__ csrp,
                                                     const uint* __restrict__ pks, const int* __restrict__ gbs,
                                                     int* __restrict__ cnts, int* __restrict__ offs, int* __restrict__ csrs,
                                                     float* __restrict__ dp1, float* __restrict__ dp2,
                                                     float* __restrict__ ds2) {
    __shared__ int h[128];
    __shared__ int sc[128];
    int bid = blockIdx.x;
    int set = (bid >= NBKT) ? 1 : 0;
    int b = bid - set * NBKT;
    const uint* packed = set ? pks : pkp;
    const int* gbase = set ? gbs : gbp;
    int* cnt = set ? cnts : cntp;
    int* off = set ? offs : offp;
    int* csr = set ? csrs : csrp;
    int t = threadIdx.x;
    int s0 = gbase[b], s1 = gbase[b + 1];
    if (t < 128) h[t] = 0;
    __syncthreads();
    for (int e = s0 + t; e < s1; e += 256) atomicAdd(&h[(packed[e] >> 17) & 127], 1);
    __syncthreads();
    int hv = 0;
    if (t < 128) { hv = h[t]; sc[t] = hv; }
    __syncthreads();
    for (int d = 1; d < 128; d <<= 1) {
        int a = (t >= d && t < 128) ? sc[t - d] : 0;
        __syncthreads();
        if (t < 128) sc[t] += a;
        __syncthreads();
    }
    int excl = 0;
    if (t < 128) excl = sc[t] - hv;
    __syncthreads();
    if (t < 128) h[t] = excl;      // reuse as per-node cursor
    int node = b * 128 + t;
    if (t < 128 && node < NN) {
        cnt[node] = hv;
        off[node] = s0 + excl;
        float fv = (float)hv;
        if (set == 0) {            // pri: dp1, dp2
            dp1[node] = rsqrtf(fv + 0.3f);
            dp2[node] = rsqrtf(fv + 0.5f);
        } else {                   // sup: ds2
            ds2[node] = rsqrtf(fv + 0.5f);
        }
    }
    __syncthreads();
    for (int e = s0 + t; e < s1; e += 256) {
        uint pc = packed[e];
        int rk = atomicAdd(&h[(pc >> 17) & 127], 1);
        csr[s0 + rk] = (int)(pc & 0x1FFFFu);
    }
}

// ---------------- MFMA dual GEMM -> bf16 g-tables (gA interleaved 256B rows + g2s) ----------------
// gA row layout per node (128 ushorts): [0..63] = g1 = h1*dp1, [64..127] = g2p = h2*dp2
__global__ __launch_bounds__(256) void gemm_kernel(const float* __restrict__ x,
                                                   const uint4* __restrict__ wfrag,
                                                   const float* __restrict__ b1, const float* __restrict__ b2,
                                                   const float* __restrict__ dp1, const float* __restrict__ dp2,
                                                   const float* __restrict__ ds2,
                                                   ushort* __restrict__ gA, ushort* __restrict__ g2s) {
    __shared__ uint4 alds[32 * 68];   // 34 KB, 17-unit swizzle
    int t = threadIdx.x;
    int lane = t & 63;
    int wave = t >> 6;
    int row0 = blockIdx.x * 128;

    FragU bfrag[2][4];
#pragma unroll
    for (int ctl = 0; ctl < 2; ctl++)
#pragma unroll
        for (int ks = 0; ks < 4; ks++)
            bfrag[ctl][ks].u = wfrag[((wave * 2 + ctl) * 4 + ks) * 64 + lane];

    {
        int m = t >> 4;
        int g = t & 15;
        const float4* xv = (const float4*)x;
#pragma unroll
        for (int s = 0; s < 8; s++) {
            int r = row0 + s * 16 + m;
            int rc = (r < NN) ? r : (NN - 1);
            float4 p0 = xv[rc * 32 + g * 2];
            float4 p1 = xv[rc * 32 + g * 2 + 1];
            uint4 q;
            q.x = pack2bf(p0.x, p0.y);
            q.y = pack2bf(p0.z, p0.w);
            q.z = pack2bf(p1.x, p1.y);
            q.w = pack2bf(p1.z, p1.w);
            alds[(s * 4 + (g >> 2)) * 68 + (g & 3) * 17 + m] = q;
        }
    }
    __syncthreads();

    int cA = (wave * 2 + 0) * 16 + (lane & 15);
    int cB = cA + 16;
    float biasA = (wave < 2) ? b1[cA] : b2[cA - 64];
    float biasB = (wave < 2) ? b1[cB] : b2[cB - 64];
    float4a acc[8][2];
#pragma unroll
    for (int rt = 0; rt < 8; rt++) {
        acc[rt][0] = float4a{biasA, biasA, biasA, biasA};
        acc[rt][1] = float4a{biasB, biasB, biasB, biasB};
    }

    int quad = lane >> 4;
    int asig = quad * 17 + (lane & 15);
#pragma unroll
    for (int rt = 0; rt < 8; rt++) {
        FragU af[4];
#pragma unroll
        for (int ks = 0; ks < 4; ks++)
            af[ks].u = alds[(rt * 4 + ks) * 68 + asig];
#pragma unroll
        for (int ks = 0; ks < 4; ks++) {
            acc[rt][0] = __builtin_amdgcn_mfma_f32_16x16x32_bf16(af[ks].s, bfrag[0][ks].s, acc[rt][0], 0, 0, 0);
            acc[rt][1] = __builtin_amdgcn_mfma_f32_16x16x32_bf16(af[ks].s, bfrag[1][ks].s, acc[rt][1], 0, 0, 0);
        }
    }

#pragma unroll
    for (int rt = 0; rt < 8; rt++) {
        int rb = row0 + rt * 16 + quad * 4;
#pragma unroll
        for (int ctl = 0; ctl < 2; ctl++) {
            int c = (wave * 2 + ctl) * 16 + (lane & 15);
#pragma unroll
            for (int reg = 0; reg < 4; reg++) {
                int r = rb + reg;
                if (r >= NN) continue;
                float v = acc[rt][ctl][reg];
                if (wave < 2) {
                    gA[r * 128 + c] = f2bf(v * dp1[r]);              // g1 half
                } else {
                    int cc = c - 64;
                    gA[r * 128 + 64 + cc] = f2bf(v * dp2[r]);        // g2p half
                    g2s[r * 64 + cc] = f2bf(v * ds2[r]);
                }
            }
        }
    }
}

// ---------------- fused hop 1: pri pair from gA (256B rows), sup from g2s ----------------
// writes gB (interleaved [gt1|gtp] 256B rows) + gts
__global__ __launch_bounds__(256) void spmm1_kernel(
        const uint* __restrict__ gA, const uint* __restrict__ g2s,
        ushort* __restrict__ gB, ushort* __restrict__ gts,
        const int* __restrict__ off_p, const int* __restrict__ cnt_p, const int* __restrict__ csr_p,
        const int* __restrict__ off_s, const int* __restrict__ cnt_s, const int* __restrict__ csr_s,
        const float* __restrict__ dvp1, const float* __restrict__ dvp2, const float* __restrict__ dvs2) {
    int tid = blockIdx.x * 256 + threadIdx.x;
    int node = tid >> 3;
    if (node >= NN) return;
    int fc = tid & 7;
    const uint4* gav = (const uint4*)gA;
    const uint4* gsv = (const uint4*)g2s;

    float a1[8] = {0, 0, 0, 0, 0, 0, 0, 0};
    float ap[8] = {0, 0, 0, 0, 0, 0, 0, 0};
    float as[8] = {0, 0, 0, 0, 0, 0, 0, 0};

    {   // pri edges: one 256B combined row per edge
        int o = off_p[node], c = cnt_p[node];
        int e = 0;
        for (; e + 1 < c; e += 2) {
            int s0 = csr_p[o + e], s1 = csr_p[o + e + 1];
            uint4 qa0 = gav[s0 * 16 + fc];
            uint4 qb0 = gav[s0 * 16 + 8 + fc];
            uint4 qa1 = gav[s1 * 16 + fc];
            uint4 qb1 = gav[s1 * 16 + 8 + fc];
            qadd(a1, qa0); qadd(ap, qb0);
            qadd(a1, qa1); qadd(ap, qb1);
        }
        if (e < c) {
            int s0 = csr_p[o + e];
            qadd(a1, gav[s0 * 16 + fc]);
            qadd(ap, gav[s0 * 16 + 8 + fc]);
        }
    }
    {   // sup edges
        int o = off_s[node], c = cnt_s[node];
        int e = 0;
        for (; e + 3 < c; e += 4) {
            int s0 = csr_s[o + e], s1 = csr_s[o + e + 1];
            int s2 = csr_s[o + e + 2], s3 = csr_s[o + e + 3];
            uint4 q0 = gsv[s0 * 8 + fc];
            uint4 q1 = gsv[s1 * 8 + fc];
            uint4 q2 = gsv[s2 * 8 + fc];
            uint4 q3 = gsv[s3 * 8 + fc];
            qadd(as, q0); qadd(as, q1); qadd(as, q2); qadd(as, q3);
        }
        for (; e < c; e++) qadd(as, gsv[csr_s[o + e] * 8 + fc]);
    }

    float dp1 = dvp1[node], dp2 = dvp2[node], ds2 = dvs2[node];
    float sp1 = 0.7f + 0.3f * dp1 * dp1;
    float sp2 = 0.5f + 0.5f * dp2 * dp2;
    float ss2 = 0.5f + 0.5f * ds2 * ds2;
    // self-term coefficients applied directly to own table rows: h = g_own/d
    float c1 = sp1 / dp1;
    float cp = sp2 / dp2;
    float cs = ss2 / dp2;   // z2s self uses h2 = g2p_own/dp2

    float t1f[8], tpf[8];
    qset(t1f, gav[node * 16 + fc]);
    qset(tpf, gav[node * 16 + 8 + fc]);

    float o1[8], op[8], os[8];
#pragma unroll
    for (int i = 0; i < 8; i++) {
        o1[i] = c1 * t1f[i] + dp1 * a1[i];
        op[i] = cp * tpf[i] + dp2 * ap[i];
        os[i] = cs * tpf[i] + ds2 * as[i];
    }

    uint4a q;
    q.x = pack2bf(o1[0] * dp1, o1[1] * dp1);
    q.y = pack2bf(o1[2] * dp1, o1[3] * dp1);
    q.z = pack2bf(o1[4] * dp1, o1[5] * dp1);
    q.w = pack2bf(o1[6] * dp1, o1[7] * dp1);
    __builtin_nontemporal_store(q, ((uint4a*)gB) + node * 16 + fc);
    q.x = pack2bf(op[0] * dp2, op[1] * dp2);
    q.y = pack2bf(op[2] * dp2, op[3] * dp2);
    q.z = pack2bf(op[4] * dp2, op[5] * dp2);
    q.w = pack2bf(op[6] * dp2, op[7] * dp2);
    __builtin_nontemporal_store(q, ((uint4a*)gB) + node * 16 + 8 + fc);
    q.x = pack2bf(os[0] * ds2, os[1] * ds2);
    q.y = pack2bf(os[2] * ds2, os[3] * ds2);
    q.z = pack2bf(os[4] * ds2, os[5] * ds2);
    q.w = pack2bf(os[6] * ds2, os[7] * ds2);
    __builtin_nontemporal_store(q, ((uint4a*)gts) + node * 8 + fc);
}

// ---------------- fused hop 2: final outputs, pri pair from gB, sup from gts ----------------
__global__ __launch_bounds__(256) void spmm2_kernel(
        const uint* __restrict__ gB, const uint* __restrict__ gts,
        const int* __restrict__ off_p, const int* __restrict__ cnt_p, const int* __restrict__ csr_p,
        const int* __restrict__ off_s, const int* __restrict__ cnt_s, const int* __restrict__ csr_s,
        const float* __restrict__ dvp1, const float* __restrict__ dvp2, const float* __restrict__ dvs2,
        float* __restrict__ out1, float* __restrict__ out2) {
    int tid = blockIdx.x * 256 + threadIdx.x;
    int node = tid >> 3;
    if (node >= NN) return;
    int fc = tid & 7;
    const uint4* gbv = (const uint4*)gB;
    const uint4* gsv = (const uint4*)gts;

    float a1[8] = {0, 0, 0, 0, 0, 0, 0, 0};
    float ap[8] = {0, 0, 0, 0, 0, 0, 0, 0};
    float as[8] = {0, 0, 0, 0, 0, 0, 0, 0};

    {   // pri edges: one 256B combined row per edge
        int o = off_p[node], c = cnt_p[node];
        int e = 0;
        for (; e + 1 < c; e += 2) {
            int s0 = csr_p[o + e], s1 = csr_p[o + e + 1];
            uint4 qa0 = gbv[s0 * 16 + fc];
            uint4 qb0 = gbv[s0 * 16 + 8 + fc];
            uint4 qa1 = gbv[s1 * 16 + fc];
            uint4 qb1 = gbv[s1 * 16 + 8 + fc];
            qadd(a1, qa0); qadd(ap, qb0);
            qadd(a1, qa1); qadd(ap, qb1);
        }
        if (e < c) {
            int s0 = csr_p[o + e];
            qadd(a1, gbv[s0 * 16 + fc]);
            qadd(ap, gbv[s0 * 16 + 8 + fc]);
        }
    }
    {
        int o = off_s[node], c = cnt_s[node];
        int e = 0;
        for (; e + 3 < c; e += 4) {
            int s0 = csr_s[o + e], s1 = csr_s[o + e + 1];
            int s2 = csr_s[o + e + 2], s3 = csr_s[o + e + 3];
            uint4 q0 = gsv[s0 * 8 + fc];
            uint4 q1 = gsv[s1 * 8 + fc];
            uint4 q2 = gsv[s2 * 8 + fc];
            uint4 q3 = gsv[s3 * 8 + fc];
            qadd(as, q0); qadd(as, q1); qadd(as, q2); qadd(as, q3);
        }
        for (; e < c; e++) qadd(as, gsv[csr_s[o + e] * 8 + fc]);
    }

    float dp1 = dvp1[node], dp2 = dvp2[node], ds2 = dvs2[node];
    float sp1 = 0.7f + 0.3f * dp1 * dp1;
    float sp2 = 0.5f + 0.5f * dp2 * dp2;
    float ss2 = 0.5f + 0.5f * ds2 * ds2;
    float c1 = sp1 / dp1;
    float cp = sp2 / dp2;
    float cs = ss2 / ds2;

    float t1f[8], tpf[8], tsf[8];
    qset(t1f, gbv[node * 16 + fc]);
    qset(tpf, gbv[node * 16 + 8 + fc]);
    qset(tsf, gsv[node * 8 + fc]);

    float oz1[8], oz2[8];
#pragma unroll
    for (int i = 0; i < 8; i++) {
        oz1[i] = c1 * t1f[i] + dp1 * a1[i];
        oz2[i] = (cp * tpf[i] + dp2 * ap[i]) + (cs * tsf[i] + ds2 * as[i]);
    }

    float4a* o1v = (float4a*)out1;
    float4a* o2v = (float4a*)out2;
    float4a v;
    v.x = oz1[0]; v.y = oz1[1]; v.z = oz1[2]; v.w = oz1[3];
    __builtin_nontemporal_store(v, o1v + node * 16 + fc * 2);
    v.x = oz1[4]; v.y = oz1[5]; v.z = oz1[6]; v.w = oz1[7];
    __builtin_nontemporal_store(v, o1v + node * 16 + fc * 2 + 1);
    v.x = oz2[0]; v.y = oz2[1]; v.z = oz2[2]; v.w = oz2[3];
    __builtin_nontemporal_store(v, o2v + node * 16 + fc * 2);
    v.x = oz2[4]; v.y = oz2[5]; v.z = oz2[6]; v.w = oz2[7];
    __builtin_nontemporal_store(v, o2v + node * 16 + fc * 2 + 1);
}

extern "C" void kernel_launch(void* const* d_in, const int* in_sizes, int n_in,
                              void* d_out, int out_size, void* d_ws, size_t ws_size,
                              hipStream_t stream) {
    const float* x  = (const float*)d_in[0];
    const int* pri  = (const int*)d_in[1];
    const int* sup  = (const int*)d_in[2];
    const float* w1 = (const float*)d_in[3];
    const float* b1 = (const float*)d_in[4];
    const float* w2 = (const float*)d_in[5];
    const float* b2 = (const float*)d_in[6];
    float* out = (float*)d_out;

    char* ws = (char*)d_ws;
    auto alloc = [&](size_t bytes) -> char* {
        char* p = ws;
        ws += (bytes + 255) & ~(size_t)255;
        return p;
    };
    int* cnt_p  = (int*)alloc(NN * 4);
    int* cnt_s  = (int*)alloc(NN * 4);
    int* off_p  = (int*)alloc(NN * 4);
    int* off_s  = (int*)alloc(NN * 4);
    int* ghist_p = (int*)alloc((NBKT + 1) * 4);
    int* ghist_s = (int*)alloc((NBKT + 1) * 4);
    int* gbase_p = (int*)alloc((NBKT + 1) * 4);
    int* gbase_s = (int*)alloc((NBKT + 1) * 4);
    int* gcur_p  = (int*)alloc((NBKT + 1) * 4);
    int* gcur_s  = (int*)alloc((NBKT + 1) * 4);
    int* csr_p  = (int*)alloc((size_t)EE * 4);
    int* csr_s  = (int*)alloc((size_t)EE * 4);
    float* dv_p1 = (float*)alloc(NN * 4);
    float* dv_p2 = (float*)alloc(NN * 4);
    float* dv_s2 = (float*)alloc(NN * 4);
    uint4* wfrag = (uint4*)alloc(2048 * 16);
    ushort* gA  = (ushort*)alloc((size_t)NN * 128 * 2);   // [g1|g2p] interleaved, 25.6 MB
    ushort* g2s = (ushort*)alloc((size_t)NN * HH * 2);
    ushort* gB  = (ushort*)alloc((size_t)NN * 128 * 2);   // [gt1|gtp] interleaved, 25.6 MB
    ushort* gts = (ushort*)alloc((size_t)NN * HH * 2);
    // packed buffers alias hop-1 outputs (consumed by bfinal before spmm1 writes them)
    uint* packed_p = (uint*)gB;    // 6.4 MB <= 25.6 MB
    uint* packed_s = (uint*)gts;   // 6.4 MB <= 12.8 MB

    const int NB_SPMM = (NN * 8 + 255) / 256;       // 3125
    const int NB_GEMM = (NN + 127) / 128;           // 782

    // --- CSR build (two-level counting sort, both sets per launch) + W conversion fused ---
    zerowconv_kernel<<<12, 256, 0, stream>>>(ghist_p, ghist_s, NBKT, w1, w2, wfrag);
    bhist_kernel<<<2 * NCH, 256, 0, stream>>>(pri, sup, ghist_p, ghist_s);
    bscan_kernel<<<2, 1024, 0, stream>>>(ghist_p, gbase_p, gcur_p, ghist_s, gbase_s, gcur_s);
    bscatter_kernel<<<2 * NCH, 256, 0, stream>>>(pri, sup, gcur_p, gcur_s, packed_p, packed_s);
    bfinal_kernel<<<2 * NBKT, 256, 0, stream>>>(packed_p, gbase_p, cnt_p, off_p, csr_p,
                                                packed_s, gbase_s, cnt_s, off_s, csr_s,
                                                dv_p1, dv_p2, dv_s2);

    // --- MFMA dual GEMM (interleaved gA + g2s) ---
    gemm_kernel<<<NB_GEMM, 256, 0, stream>>>(x, wfrag, b1, b2, dv_p1, dv_p2, dv_s2,
                                             gA, g2s);

    // --- fused hop 1 (3 branches) + fused hop 2 (final z1, z2) ---
    spmm1_kernel<<<NB_SPMM, 256, 0, stream>>>((const uint*)gA, (const uint*)g2s,
                                              gB, gts,
                                              off_p, cnt_p, csr_p, off_s, cnt_s, csr_s,
                                              dv_p1, dv_p2, dv_s2);
    spmm2_kernel<<<NB_SPMM, 256, 0, stream>>>((const uint*)gB, (const uint*)gts,
                                              off_p, cnt_p, csr_p, off_s, cnt_s, csr_s,
                                              dv_p1, dv_p2, dv_s2,
                                              out, out + (size_t)NN * HH);
}

// Round 7
// 416.995 us; speedup vs baseline: 1.0632x; 1.0297x over previous
//
#include <hip/hip_runtime.h>

#define NN 100000
#define EE 1600000
#define FIN 128
#define HH 64
#define NBKT 782          // ceil(NN/128) coarse buckets
#define SCHUNK 4096       // edges per block in hist/scatter passes
#define NCH 391           // ceil(EE/SCHUNK)

typedef unsigned int uint;
typedef unsigned short ushort;
typedef __attribute__((ext_vector_type(8))) short short8;
typedef __attribute__((ext_vector_type(4))) float float4a;
typedef __attribute__((ext_vector_type(4))) uint uint4a;

union FragU { uint4 u; short8 s; };

static __device__ __forceinline__ ushort f2bf(float f) {
    uint u = __float_as_uint(f);
    uint r = (u + 0x7fffu + ((u >> 16) & 1u)) >> 16;   // RNE
    return (ushort)r;
}
static __device__ __forceinline__ uint pack2bf(float a, float b) {
    return (uint)f2bf(a) | ((uint)f2bf(b) << 16);
}
static __device__ __forceinline__ float bf2f_lo(uint u) {
    return __uint_as_float(u << 16);
}
static __device__ __forceinline__ float bf2f_hi(uint u) {
    return __uint_as_float(u & 0xffff0000u);
}
static __device__ __forceinline__ void qadd(float* a, uint4 q) {
    a[0] += bf2f_lo(q.x); a[1] += bf2f_hi(q.x);
    a[2] += bf2f_lo(q.y); a[3] += bf2f_hi(q.y);
    a[4] += bf2f_lo(q.z); a[5] += bf2f_hi(q.z);
    a[6] += bf2f_lo(q.w); a[7] += bf2f_hi(q.w);
}
static __device__ __forceinline__ void qset(float* a, uint4 q) {
    a[0] = bf2f_lo(q.x); a[1] = bf2f_hi(q.x);
    a[2] = bf2f_lo(q.y); a[3] = bf2f_hi(q.y);
    a[4] = bf2f_lo(q.z); a[5] = bf2f_hi(q.z);
    a[6] = bf2f_lo(q.w); a[7] = bf2f_hi(q.w);
}

// ---------------- fused: zero hist arrays (blocks 0-3) + W->bf16 fragment conversion (blocks 4-11) ----------------
__global__ __launch_bounds__(256) void zerowconv_kernel(int* __restrict__ a, int* __restrict__ b, int n,
                                                        const float* __restrict__ w1, const float* __restrict__ w2,
                                                        uint4* __restrict__ wfrag) {
    int bid = blockIdx.x;
    int t = threadIdx.x;
    if (bid < 4) {
        int i = bid * 256 + t;
        if (i < n) { a[i] = 0; b[i] = 0; }
        return;
    }
    int u = (bid - 4) * 256 + t;   // 0..2047
    if (u >= 2048) return;
    int lane = u & 63;
    int ks   = (u >> 6) & 3;
    int ct   = u >> 8;
    int c    = ct * 16 + (lane & 15);
    int k0   = ks * 32 + (lane >> 4) * 8;
    const float* src = (c < 64) ? (w1 + c * 128 + k0) : (w2 + (c - 64) * 128 + k0);
    float4 p0 = ((const float4*)src)[0];
    float4 p1 = ((const float4*)src)[1];
    uint4 q;
    q.x = pack2bf(p0.x, p0.y);
    q.y = pack2bf(p0.z, p0.w);
    q.z = pack2bf(p1.x, p1.y);
    q.w = pack2bf(p1.z, p1.w);
    wfrag[u] = q;
}

// ---------------- pass 1: coarse bucket histogram, both sets, int4 reads ----------------
__global__ __launch_bounds__(256) void bhist_kernel(const int* __restrict__ pri, const int* __restrict__ sup,
                                                    int* __restrict__ ghp, int* __restrict__ ghs) {
    __shared__ int h[NBKT];
    int bid = blockIdx.x;
    int set = (bid >= NCH) ? 1 : 0;
    int chunk = bid - set * NCH;
    const int* col = (set ? sup : pri) + EE;
    int* gh = set ? ghs : ghp;
    int t = threadIdx.x;
    for (int i = t; i < NBKT; i += 256) h[i] = 0;
    __syncthreads();
    int e0 = chunk * SCHUNK;
    int e1 = min(e0 + SCHUNK, EE);
    for (int e = e0 + t * 4; e < e1; e += 1024) {
        int4 c4 = *(const int4*)(col + e);
        atomicAdd(&h[c4.x >> 7], 1);
        atomicAdd(&h[c4.y >> 7], 1);
        atomicAdd(&h[c4.z >> 7], 1);
        atomicAdd(&h[c4.w >> 7], 1);
    }
    __syncthreads();
    for (int i = t; i < NBKT; i += 256) {
        int v = h[i];
        if (v) atomicAdd(&gh[i], v);
    }
}

// ---------------- pass 2: bucket base scan, block 0 = pri, block 1 = sup ----------------
__global__ __launch_bounds__(1024) void bscan_kernel(const int* __restrict__ ghp, int* __restrict__ gbp, int* __restrict__ gcp,
                                                     const int* __restrict__ ghs, int* __restrict__ gbs, int* __restrict__ gcs) {
    __shared__ int s[1024];
    const int* gh = blockIdx.x ? ghs : ghp;
    int* gb = blockIdx.x ? gbs : gbp;
    int* gc = blockIdx.x ? gcs : gcp;
    int t = threadIdx.x;
    int v = (t < NBKT) ? gh[t] : 0;
    s[t] = v;
    __syncthreads();
    for (int d = 1; d < 1024; d <<= 1) {
        int a = (t >= d) ? s[t - d] : 0;
        __syncthreads();
        s[t] += a;
        __syncthreads();
    }
    int excl = s[t] - v;
    if (t <= NBKT) gb[t] = excl;   // gb[NBKT] = EE
    if (t < NBKT) gc[t] = excl;
}

// ---------------- pass 3: binned scatter (packed uint: row | fine<<17), both sets ----------------
__global__ __launch_bounds__(256) void bscatter_kernel(const int* __restrict__ pri, const int* __restrict__ sup,
                                                       int* __restrict__ gcp, int* __restrict__ gcs,
                                                       uint* __restrict__ pkp, uint* __restrict__ pks) {
    __shared__ int h[NBKT];
    __shared__ int basec[NBKT];
    int bid = blockIdx.x;
    int set = (bid >= NCH) ? 1 : 0;
    int chunk = bid - set * NCH;
    const int* row = set ? sup : pri;
    const int* col = row + EE;
    int* gcur = set ? gcs : gcp;
    uint* packed = set ? pks : pkp;
    int t = threadIdx.x;
    for (int i = t; i < NBKT; i += 256) h[i] = 0;
    __syncthreads();
    int e0 = chunk * SCHUNK;
    int e1 = min(e0 + SCHUNK, EE);
    for (int e = e0 + t * 4; e < e1; e += 1024) {
        int4 c4 = *(const int4*)(col + e);
        atomicAdd(&h[c4.x >> 7], 1);
        atomicAdd(&h[c4.y >> 7], 1);
        atomicAdd(&h[c4.z >> 7], 1);
        atomicAdd(&h[c4.w >> 7], 1);
    }
    __syncthreads();
    for (int i = t; i < NBKT; i += 256) {
        int v = h[i];
        basec[i] = v ? atomicAdd(&gcur[i], v) : 0;
    }
    __syncthreads();
    for (int i = t; i < NBKT; i += 256) h[i] = 0;
    __syncthreads();
    for (int e = e0 + t * 4; e < e1; e += 1024) {
        int4 c4 = *(const int4*)(col + e);
        int4 r4 = *(const int4*)(row + e);
        int b0 = c4.x >> 7, b1 = c4.y >> 7, b2 = c4.z >> 7, b3 = c4.w >> 7;
        int p0 = basec[b0] + atomicAdd(&h[b0], 1);
        int p1 = basec[b1] + atomicAdd(&h[b1], 1);
        int p2 = basec[b2] + atomicAdd(&h[b2], 1);
        int p3 = basec[b3] + atomicAdd(&h[b3], 1);
        packed[p0] = (uint)r4.x | ((uint)(c4.x & 127) << 17);
        packed[p1] = (uint)r4.y | ((uint)(c4.y & 127) << 17);
        packed[p2] = (uint)r4.z | ((uint)(c4.z & 127) << 17);
        packed[p3] = (uint)r4.w | ((uint)(c4.w & 127) << 17);
    }
}

// ---------------- pass 4: per-bucket CSR finalize + cnt/off + fused dinv, both sets ----------------
__global__ __launch_bounds__(256) void bfinal_kernel(const uint* __restrict__ pkp, const int* __restrict__ gbp,
                                                     int* __restrict__ cntp, int* __restrict__ offp, int* __restrict__ csrp,
                                                     const uint* __restrict__ pks, const int* __restrict__ gbs,
                                                     int* __restrict__ cnts, int* __restrict__ offs, int* __restrict__ csrs,
                                                     float* __restrict__ dp1, float* __restrict__ dp2,
                                                     float* __restrict__ ds2) {
    __shared__ int h[128];
    __shared__ int sc[128];
    int bid = blockIdx.x;
    int set = (bid >= NBKT) ? 1 : 0;
    int b = bid - set * NBKT;
    const uint* packed = set ? pks : pkp;
    const int* gbase = set ? gbs : gbp;
    int* cnt = set ? cnts : cntp;
    int* off = set ? offs : offp;
    int* csr = set ? csrs : csrp;
    int t = threadIdx.x;
    int s0 = gbase[b], s1 = gbase[b + 1];
    if (t < 128) h[t] = 0;
    __syncthreads();
    for (int e = s0 + t; e < s1; e += 256) atomicAdd(&h[(packed[e] >> 17) & 127], 1);
    __syncthreads();
    int hv = 0;
    if (t < 128) { hv = h[t]; sc[t] = hv; }
    __syncthreads();
    for (int d = 1; d < 128; d <<= 1) {
        int a = (t >= d && t < 128) ? sc[t - d] : 0;
        __syncthreads();
        if (t < 128) sc[t] += a;
        __syncthreads();
    }
    int excl = 0;
    if (t < 128) excl = sc[t] - hv;
    __syncthreads();
    if (t < 128) h[t] = excl;      // reuse as per-node cursor
    int node = b * 128 + t;
    if (t < 128 && node < NN) {
        cnt[node] = hv;
        off[node] = s0 + excl;
        float fv = (float)hv;
        if (set == 0) {            // pri: dp1, dp2
            dp1[node] = rsqrtf(fv + 0.3f);
            dp2[node] = rsqrtf(fv + 0.5f);
        } else {                   // sup: ds2
            ds2[node] = rsqrtf(fv + 0.5f);
        }
    }
    __syncthreads();
    for (int e = s0 + t; e < s1; e += 256) {
        uint pc = packed[e];
        int rk = atomicAdd(&h[(pc >> 17) & 127], 1);
        csr[s0 + rk] = (int)(pc & 0x1FFFFu);
    }
}

// ---------------- MFMA dual GEMM -> bf16 g-tables only (R0 layout: 3 separate 128B-row tables) ----------------
__global__ __launch_bounds__(256) void gemm_kernel(const float* __restrict__ x,
                                                   const uint4* __restrict__ wfrag,
                                                   const float* __restrict__ b1, const float* __restrict__ b2,
                                                   const float* __restrict__ dp1, const float* __restrict__ dp2,
                                                   const float* __restrict__ ds2,
                                                   ushort* __restrict__ g1, ushort* __restrict__ g2s,
                                                   ushort* __restrict__ g2p) {
    __shared__ uint4 alds[32 * 68];   // 34 KB, 17-unit swizzle
    int t = threadIdx.x;
    int lane = t & 63;
    int wave = t >> 6;
    int row0 = blockIdx.x * 128;

    FragU bfrag[2][4];
#pragma unroll
    for (int ctl = 0; ctl < 2; ctl++)
#pragma unroll
        for (int ks = 0; ks < 4; ks++)
            bfrag[ctl][ks].u = wfrag[((wave * 2 + ctl) * 4 + ks) * 64 + lane];

    {
        int m = t >> 4;
        int g = t & 15;
        const float4* xv = (const float4*)x;
#pragma unroll
        for (int s = 0; s < 8; s++) {
            int r = row0 + s * 16 + m;
            int rc = (r < NN) ? r : (NN - 1);
            float4 p0 = xv[rc * 32 + g * 2];
            float4 p1 = xv[rc * 32 + g * 2 + 1];
            uint4 q;
            q.x = pack2bf(p0.x, p0.y);
            q.y = pack2bf(p0.z, p0.w);
            q.z = pack2bf(p1.x, p1.y);
            q.w = pack2bf(p1.z, p1.w);
            alds[(s * 4 + (g >> 2)) * 68 + (g & 3) * 17 + m] = q;
        }
    }
    __syncthreads();

    int cA = (wave * 2 + 0) * 16 + (lane & 15);
    int cB = cA + 16;
    float biasA = (wave < 2) ? b1[cA] : b2[cA - 64];
    float biasB = (wave < 2) ? b1[cB] : b2[cB - 64];
    float4a acc[8][2];
#pragma unroll
    for (int rt = 0; rt < 8; rt++) {
        acc[rt][0] = float4a{biasA, biasA, biasA, biasA};
        acc[rt][1] = float4a{biasB, biasB, biasB, biasB};
    }

    int quad = lane >> 4;
    int asig = quad * 17 + (lane & 15);
#pragma unroll
    for (int rt = 0; rt < 8; rt++) {
        FragU af[4];
#pragma unroll
        for (int ks = 0; ks < 4; ks++)
            af[ks].u = alds[(rt * 4 + ks) * 68 + asig];
#pragma unroll
        for (int ks = 0; ks < 4; ks++) {
            acc[rt][0] = __builtin_amdgcn_mfma_f32_16x16x32_bf16(af[ks].s, bfrag[0][ks].s, acc[rt][0], 0, 0, 0);
            acc[rt][1] = __builtin_amdgcn_mfma_f32_16x16x32_bf16(af[ks].s, bfrag[1][ks].s, acc[rt][1], 0, 0, 0);
        }
    }

#pragma unroll
    for (int rt = 0; rt < 8; rt++) {
        int rb = row0 + rt * 16 + quad * 4;
#pragma unroll
        for (int ctl = 0; ctl < 2; ctl++) {
            int c = (wave * 2 + ctl) * 16 + (lane & 15);
#pragma unroll
            for (int reg = 0; reg < 4; reg++) {
                int r = rb + reg;
                if (r >= NN) continue;
                float v = acc[rt][ctl][reg];
                if (wave < 2) {
                    g1[r * 64 + c] = f2bf(v * dp1[r]);
                } else {
                    int cc = c - 64;
                    g2s[r * 64 + cc] = f2bf(v * ds2[r]);
                    g2p[r * 64 + cc] = f2bf(v * dp2[r]);
                }
            }
        }
    }
}

// ---------------- fused hop 1: 3 branches, g-only dataflow (R0 structure) ----------------
__global__ __launch_bounds__(256) void spmm1_kernel(
        const uint* __restrict__ g1, const uint* __restrict__ g2p, const uint* __restrict__ g2s,
        ushort* __restrict__ gt1, ushort* __restrict__ gtp, ushort* __restrict__ gts,
        const int* __restrict__ off_p, const int* __restrict__ cnt_p, const int* __restrict__ csr_p,
        const int* __restrict__ off_s, const int* __restrict__ cnt_s, const int* __restrict__ csr_s,
        const float* __restrict__ dvp1, const float* __restrict__ dvp2, const float* __restrict__ dvs2) {
    int tid = blockIdx.x * 256 + threadIdx.x;
    int node = tid >> 3;
    if (node >= NN) return;
    int fc = tid & 7;
    const uint4* g1v = (const uint4*)g1;
    const uint4* gpv = (const uint4*)g2p;
    const uint4* gsv = (const uint4*)g2s;

    float a1[8] = {0, 0, 0, 0, 0, 0, 0, 0};
    float ap[8] = {0, 0, 0, 0, 0, 0, 0, 0};
    float as[8] = {0, 0, 0, 0, 0, 0, 0, 0};

    {   // pri edges: two tables per edge
        int o = off_p[node], c = cnt_p[node];
        int e = 0;
        for (; e + 1 < c; e += 2) {
            int s0 = csr_p[o + e], s1 = csr_p[o + e + 1];
            uint4 qa0 = g1v[s0 * 8 + fc];
            uint4 qb0 = gpv[s0 * 8 + fc];
            uint4 qa1 = g1v[s1 * 8 + fc];
            uint4 qb1 = gpv[s1 * 8 + fc];
            qadd(a1, qa0); qadd(ap, qb0);
            qadd(a1, qa1); qadd(ap, qb1);
        }
        if (e < c) {
            int s0 = csr_p[o + e];
            qadd(a1, g1v[s0 * 8 + fc]);
            qadd(ap, gpv[s0 * 8 + fc]);
        }
    }
    {   // sup edges
        int o = off_s[node], c = cnt_s[node];
        int e = 0;
        for (; e + 3 < c; e += 4) {
            int s0 = csr_s[o + e], s1 = csr_s[o + e + 1];
            int s2 = csr_s[o + e + 2], s3 = csr_s[o + e + 3];
            uint4 q0 = gsv[s0 * 8 + fc];
            uint4 q1 = gsv[s1 * 8 + fc];
            uint4 q2 = gsv[s2 * 8 + fc];
            uint4 q3 = gsv[s3 * 8 + fc];
            qadd(as, q0); qadd(as, q1); qadd(as, q2); qadd(as, q3);
        }
        for (; e < c; e++) qadd(as, gsv[csr_s[o + e] * 8 + fc]);
    }

    float dp1 = dvp1[node], dp2 = dvp2[node], ds2 = dvs2[node];
    float sp1 = 0.7f + 0.3f * dp1 * dp1;
    float sp2 = 0.5f + 0.5f * dp2 * dp2;
    float ss2 = 0.5f + 0.5f * ds2 * ds2;
    // self-term coefficients applied directly to own table rows: h = g_own/d
    float c1 = sp1 / dp1;
    float cp = sp2 / dp2;
    float cs = ss2 / dp2;   // z2s self uses h2 = g2p_own/dp2

    float t1f[8], tpf[8];
    qset(t1f, g1v[node * 8 + fc]);
    qset(tpf, gpv[node * 8 + fc]);

    float o1[8], op[8], os[8];
#pragma unroll
    for (int i = 0; i < 8; i++) {
        o1[i] = c1 * t1f[i] + dp1 * a1[i];
        op[i] = cp * tpf[i] + dp2 * ap[i];
        os[i] = cs * tpf[i] + ds2 * as[i];
    }

    uint4a q;
    q.x = pack2bf(o1[0] * dp1, o1[1] * dp1);
    q.y = pack2bf(o1[2] * dp1, o1[3] * dp1);
    q.z = pack2bf(o1[4] * dp1, o1[5] * dp1);
    q.w = pack2bf(o1[6] * dp1, o1[7] * dp1);
    __builtin_nontemporal_store(q, ((uint4a*)gt1) + node * 8 + fc);
    q.x = pack2bf(op[0] * dp2, op[1] * dp2);
    q.y = pack2bf(op[2] * dp2, op[3] * dp2);
    q.z = pack2bf(op[4] * dp2, op[5] * dp2);
    q.w = pack2bf(op[6] * dp2, op[7] * dp2);
    __builtin_nontemporal_store(q, ((uint4a*)gtp) + node * 8 + fc);
    q.x = pack2bf(os[0] * ds2, os[1] * ds2);
    q.y = pack2bf(os[2] * ds2, os[3] * ds2);
    q.z = pack2bf(os[4] * ds2, os[5] * ds2);
    q.w = pack2bf(os[6] * ds2, os[7] * ds2);
    __builtin_nontemporal_store(q, ((uint4a*)gts) + node * 8 + fc);
}

// ---------------- fused hop 2: final outputs, z2 = pri + sup fused (R0 structure) ----------------
__global__ __launch_bounds__(256) void spmm2_kernel(
        const uint* __restrict__ gt1, const uint* __restrict__ gtp, const uint* __restrict__ gts,
        const int* __restrict__ off_p, const int* __restrict__ cnt_p, const int* __restrict__ csr_p,
        const int* __restrict__ off_s, const int* __restrict__ cnt_s, const int* __restrict__ csr_s,
        const float* __restrict__ dvp1, const float* __restrict__ dvp2, const float* __restrict__ dvs2,
        float* __restrict__ out1, float* __restrict__ out2) {
    int tid = blockIdx.x * 256 + threadIdx.x;
    int node = tid >> 3;
    if (node >= NN) return;
    int fc = tid & 7;
    const uint4* g1v = (const uint4*)gt1;
    const uint4* gpv = (const uint4*)gtp;
    const uint4* gsv = (const uint4*)gts;

    float a1[8] = {0, 0, 0, 0, 0, 0, 0, 0};
    float ap[8] = {0, 0, 0, 0, 0, 0, 0, 0};
    float as[8] = {0, 0, 0, 0, 0, 0, 0, 0};

    {
        int o = off_p[node], c = cnt_p[node];
        int e = 0;
        for (; e + 1 < c; e += 2) {
            int s0 = csr_p[o + e], s1 = csr_p[o + e + 1];
            uint4 qa0 = g1v[s0 * 8 + fc];
            uint4 qb0 = gpv[s0 * 8 + fc];
            uint4 qa1 = g1v[s1 * 8 + fc];
            uint4 qb1 = gpv[s1 * 8 + fc];
            qadd(a1, qa0); qadd(ap, qb0);
            qadd(a1, qa1); qadd(ap, qb1);
        }
        if (e < c) {
            int s0 = csr_p[o + e];
            qadd(a1, g1v[s0 * 8 + fc]);
            qadd(ap, gpv[s0 * 8 + fc]);
        }
    }
    {
        int o = off_s[node], c = cnt_s[node];
        int e = 0;
        for (; e + 3 < c; e += 4) {
            int s0 = csr_s[o + e], s1 = csr_s[o + e + 1];
            int s2 = csr_s[o + e + 2], s3 = csr_s[o + e + 3];
            uint4 q0 = gsv[s0 * 8 + fc];
            uint4 q1 = gsv[s1 * 8 + fc];
            uint4 q2 = gsv[s2 * 8 + fc];
            uint4 q3 = gsv[s3 * 8 + fc];
            qadd(as, q0); qadd(as, q1); qadd(as, q2); qadd(as, q3);
        }
        for (; e < c; e++) qadd(as, gsv[csr_s[o + e] * 8 + fc]);
    }

    float dp1 = dvp1[node], dp2 = dvp2[node], ds2 = dvs2[node];
    float sp1 = 0.7f + 0.3f * dp1 * dp1;
    float sp2 = 0.5f + 0.5f * dp2 * dp2;
    float ss2 = 0.5f + 0.5f * ds2 * ds2;
    float c1 = sp1 / dp1;
    float cp = sp2 / dp2;
    float cs = ss2 / ds2;

    float t1f[8], tpf[8], tsf[8];
    qset(t1f, g1v[node * 8 + fc]);
    qset(tpf, gpv[node * 8 + fc]);
    qset(tsf, gsv[node * 8 + fc]);

    float oz1[8], oz2[8];
#pragma unroll
    for (int i = 0; i < 8; i++) {
        oz1[i] = c1 * t1f[i] + dp1 * a1[i];
        oz2[i] = (cp * tpf[i] + dp2 * ap[i]) + (cs * tsf[i] + ds2 * as[i]);
    }

    float4a* o1v = (float4a*)out1;
    float4a* o2v = (float4a*)out2;
    float4a v;
    v.x = oz1[0]; v.y = oz1[1]; v.z = oz1[2]; v.w = oz1[3];
    __builtin_nontemporal_store(v, o1v + node * 16 + fc * 2);
    v.x = oz1[4]; v.y = oz1[5]; v.z = oz1[6]; v.w = oz1[7];
    __builtin_nontemporal_store(v, o1v + node * 16 + fc * 2 + 1);
    v.x = oz2[0]; v.y = oz2[1]; v.z = oz2[2]; v.w = oz2[3];
    __builtin_nontemporal_store(v, o2v + node * 16 + fc * 2);
    v.x = oz2[4]; v.y = oz2[5]; v.z = oz2[6]; v.w = oz2[7];
    __builtin_nontemporal_store(v, o2v + node * 16 + fc * 2 + 1);
}

extern "C" void kernel_launch(void* const* d_in, const int* in_sizes, int n_in,
                              void* d_out, int out_size, void* d_ws, size_t ws_size,
                              hipStream_t stream) {
    const float* x  = (const float*)d_in[0];
    const int* pri  = (const int*)d_in[1];
    const int* sup  = (const int*)d_in[2];
    const float* w1 = (const float*)d_in[3];
    const float* b1 = (const float*)d_in[4];
    const float* w2 = (const float*)d_in[5];
    const float* b2 = (const float*)d_in[6];
    float* out = (float*)d_out;

    char* ws = (char*)d_ws;
    auto alloc = [&](size_t bytes) -> char* {
        char* p = ws;
        ws += (bytes + 255) & ~(size_t)255;
        return p;
    };
    int* cnt_p  = (int*)alloc(NN * 4);
    int* cnt_s  = (int*)alloc(NN * 4);
    int* off_p  = (int*)alloc(NN * 4);
    int* off_s  = (int*)alloc(NN * 4);
    int* ghist_p = (int*)alloc((NBKT + 1) * 4);
    int* ghist_s = (int*)alloc((NBKT + 1) * 4);
    int* gbase_p = (int*)alloc((NBKT + 1) * 4);
    int* gbase_s = (int*)alloc((NBKT + 1) * 4);
    int* gcur_p  = (int*)alloc((NBKT + 1) * 4);
    int* gcur_s  = (int*)alloc((NBKT + 1) * 4);
    int* csr_p  = (int*)alloc((size_t)EE * 4);
    int* csr_s  = (int*)alloc((size_t)EE * 4);
    float* dv_p1 = (float*)alloc(NN * 4);
    float* dv_p2 = (float*)alloc(NN * 4);
    float* dv_s2 = (float*)alloc(NN * 4);
    uint4* wfrag = (uint4*)alloc(2048 * 16);
    ushort* g1  = (ushort*)alloc((size_t)NN * HH * 2);
    ushort* g2s = (ushort*)alloc((size_t)NN * HH * 2);
    ushort* g2p = (ushort*)alloc((size_t)NN * HH * 2);
    ushort* gt1 = (ushort*)alloc((size_t)NN * HH * 2);
    ushort* gtp = (ushort*)alloc((size_t)NN * HH * 2);
    ushort* gts = (ushort*)alloc((size_t)NN * HH * 2);
    // packed buffers alias gt tables (consumed by bfinal before spmm1 writes gt)
    uint* packed_p = (uint*)gt1;   // 6.4 MB <= 12.8 MB
    uint* packed_s = (uint*)gtp;

    const int NB_SPMM = (NN * 8 + 255) / 256;       // 3125
    const int NB_GEMM = (NN + 127) / 128;           // 782

    // --- CSR build (two-level counting sort, both sets per launch) + W conversion fused ---
    zerowconv_kernel<<<12, 256, 0, stream>>>(ghist_p, ghist_s, NBKT, w1, w2, wfrag);
    bhist_kernel<<<2 * NCH, 256, 0, stream>>>(pri, sup, ghist_p, ghist_s);
    bscan_kernel<<<2, 1024, 0, stream>>>(ghist_p, gbase_p, gcur_p, ghist_s, gbase_s, gcur_s);
    bscatter_kernel<<<2 * NCH, 256, 0, stream>>>(pri, sup, gcur_p, gcur_s, packed_p, packed_s);
    bfinal_kernel<<<2 * NBKT, 256, 0, stream>>>(packed_p, gbase_p, cnt_p, off_p, csr_p,
                                                packed_s, gbase_s, cnt_s, off_s, csr_s,
                                                dv_p1, dv_p2, dv_s2);

    // --- MFMA dual GEMM (g-tables only) ---
    gemm_kernel<<<NB_GEMM, 256, 0, stream>>>(x, wfrag, b1, b2, dv_p1, dv_p2, dv_s2,
                                             g1, g2s, g2p);

    // --- fused hop 1 (3 branches) + fused hop 2 (final z1, z2) ---
    spmm1_kernel<<<NB_SPMM, 256, 0, stream>>>((const uint*)g1, (const uint*)g2p, (const uint*)g2s,
                                              gt1, gtp, gts,
                                              off_p, cnt_p, csr_p, off_s, cnt_s, csr_s,
                                              dv_p1, dv_p2, dv_s2);
    spmm2_kernel<<<NB_SPMM, 256, 0, stream>>>((const uint*)gt1, (const uint*)gtp, (const uint*)gts,
                                              off_p, cnt_p, csr_p, off_s, cnt_s, csr_s,
                                              dv_p1, dv_p2, dv_s2,
                                              out, out + (size_t)NN * HH);
}